// Round 3
// baseline (1697.728 us; speedup 1.0000x reference)
//
#include <hip/hip_runtime.h>
#include <math.h>

#define NTOK    8192
#define DIM     4096
#define NEXP    64
#define TOPK_N  8
#define TPW     8                 // tokens per wave
#define WAVES   2                 // waves per block
#define BLK_TOK (TPW * WAVES)     // 16 tokens per block
#define KC      64                // k per chunk
#define K4      (KC / 4)          // 16 float4 per expert per chunk
#define NCHUNK  (DIM / KC)        // 64
#define TAU     3.0e-4f
#define MAXFLAG 4096

// async global->LDS, 16B per lane, dest = uniform base + lane*16
__device__ __forceinline__ void async_load16(const float* g, float4* l) {
    __builtin_amdgcn_global_load_lds(
        (const __attribute__((address_space(1))) void*)g,
        (__attribute__((address_space(3))) void*)l, 16, 0, 0);
}

__global__ __launch_bounds__(128, 1)
void gate_kernel(const float* __restrict__ x, const float* __restrict__ w,
                 const float* __restrict__ bias, float* __restrict__ out,
                 int* __restrict__ flags, int ntok) {
    // w: double buffer, XOR-swizzled [k4][e^k4], 2*16*64*16B = 32 KB
    __shared__ float4 lw[2 * K4 * NEXP];
    // x: triple buffer, natural [t][k4], 3*16*16*16B = 12 KB
    __shared__ float4 lx[3 * BLK_TOK * K4];

    const int tid  = threadIdx.x;
    const int lane = tid & 63;
    const int wave = tid >> 6;
    const int tok_blk = blockIdx.x * BLK_TOK;

    // ---- w staging mapping: thread -> (k4, 8 experts) ----
    const int k4w = tid & 15;
    const int e0  = (tid >> 4) * 8;
    float4 wreg[8];

    // ---- x staging: 4 async wave-instrs per chunk; wave issues 2 ----
    // instr i: lane -> t = i*4 + (lane>>4), k4 = lane&15 ; LDS idx = t*16+k4 (natural)
    auto issue_x = [&](int c) {
        const int b  = c % 3;
        const int k0 = c * KC;
        #pragma unroll
        for (int ii = 0; ii < 2; ++ii) {
            const int i = wave * 2 + ii;
            const int t = i * 4 + (lane >> 4);
            const int k4 = lane & 15;
            const float* g = x + (size_t)(tok_blk + t) * DIM + k0 + k4 * 4;
            async_load16(g, &lx[b * (BLK_TOK * K4) + i * 64]);
        }
    };
    auto load_w = [&](int c) {
        const int k0 = c * KC;
        #pragma unroll
        for (int i = 0; i < 8; ++i)
            wreg[i] = *reinterpret_cast<const float4*>(
                w + (size_t)(e0 + i) * DIM + k0 + k4w * 4);
    };
    auto write_w = [&](int c) {
        float4* dst = &lw[(c & 1) * (K4 * NEXP)];
        #pragma unroll
        for (int i = 0; i < 8; ++i)
            dst[k4w * NEXP + ((e0 + i) ^ k4w)] = wreg[i];
    };

    float acc[TPW];
    #pragma unroll
    for (int t = 0; t < TPW; ++t) acc[t] = 0.f;

    // ---- prologue ----
    load_w(0);
    issue_x(0);
    write_w(0);          // compiler inserts vmcnt wait for wreg
    load_w(1);
    issue_x(1);
    __syncthreads();     // drains x0 (x1 also; it re-arrives cheaply from L2-issued queue)

    // ---- K loop: compute c | write w[c+1] | barrier | issue c+2 ----
    for (int c = 0; c < NCHUNK; ++c) {
        const float4* wb = &lw[(c & 1) * (K4 * NEXP)];
        const float4* xb = &lx[(c % 3) * (BLK_TOK * K4) + wave * TPW * K4];

        #pragma unroll
        for (int j4 = 0; j4 < K4; ++j4) {
            const float4 wv = wb[j4 * NEXP + (lane ^ j4)];
            #pragma unroll
            for (int t = 0; t < TPW; ++t) {
                const float4 xv = xb[t * K4 + j4];
                acc[t] = fmaf(xv.x, wv.x, acc[t]);
                acc[t] = fmaf(xv.y, wv.y, acc[t]);
                acc[t] = fmaf(xv.z, wv.z, acc[t]);
                acc[t] = fmaf(xv.w, wv.w, acc[t]);
            }
        }

        if (c + 1 < NCHUNK) write_w(c + 1);
        __syncthreads();
        if (c + 2 < NCHUNK) { load_w(c + 2); issue_x(c + 2); }
    }

    // ---- epilogue: softmax + top-9 gap screen (lane = expert) ----
    const float bmy = bias[lane];
    float* __restrict__ out_idx = out + (size_t)NTOK * NEXP;

    #pragma unroll
    for (int t = 0; t < TPW; ++t) {
        const int tok = tok_blk + wave * TPW + t;
        if (tok >= ntok) break;
        const float s = acc[t] + bmy;

        float m = s;
        #pragma unroll
        for (int off = 32; off > 0; off >>= 1)
            m = fmaxf(m, __shfl_xor(m, off, 64));
        const float ex = expf(s - m);
        float sum = ex;
        #pragma unroll
        for (int off = 32; off > 0; off >>= 1)
            sum += __shfl_xor(sum, off, 64);
        out[(size_t)tok * NEXP + lane] = ex / sum;

        float cv = s;
        float prev = 0.f, ming = 1e30f;
        for (int r = 0; r < TOPK_N + 1; ++r) {
            float bv = cv;
            int   bi = lane;
            #pragma unroll
            for (int off = 32; off > 0; off >>= 1) {
                const float ov = __shfl_xor(bv, off, 64);
                const int   oi = __shfl_xor(bi, off, 64);
                if (ov > bv || (ov == bv && oi < bi)) { bv = ov; bi = oi; }
            }
            if (r > 0) ming = fminf(ming, prev - bv);
            prev = bv;
            if (r < TOPK_N && lane == r)
                out_idx[(size_t)tok * TOPK_N + r] = (float)bi;
            if (lane == bi) cv = -INFINITY;
        }

        if (lane == 0 && ming < TAU) {
            const int slot = atomicAdd(flags, 1);
            if (slot < MAXFLAG) flags[1 + slot] = tok;
        }
    }
}

// ---------------- Pass 2: fp64 exact recheck, coalesced ----------------
__global__ __launch_bounds__(256, 2)
void recheck_kernel(const float* __restrict__ x, const float* __restrict__ w,
                    const float* __restrict__ bias, float* __restrict__ out,
                    const int* __restrict__ flags) {
    __shared__ double part[4][NEXP];
    int n = flags[0];
    if (n > MAXFLAG) n = MAXFLAG;
    const int lane = threadIdx.x & 63;
    const int wv   = threadIdx.x >> 6;
    const int kq   = wv * (DIM / 4);              // this wave's k-quarter
    float* __restrict__ out_idx = out + (size_t)NTOK * NEXP;

    for (int i = blockIdx.x; i < n; i += gridDim.x) {
        const int tok = flags[1 + i];
        double mysc = 0.0;
        for (int e = 0; e < NEXP; ++e) {
            double acc = 0.0;
            #pragma unroll
            for (int kk = 0; kk < 4; ++kk) {
                const int k = kq + kk * 256 + lane * 4;   // coalesced
                const float4 wv4 = *reinterpret_cast<const float4*>(w + (size_t)e * DIM + k);
                const float4 xv  = *reinterpret_cast<const float4*>(x + (size_t)tok * DIM + k);
                acc = fma((double)xv.x, (double)wv4.x, acc);
                acc = fma((double)xv.y, (double)wv4.y, acc);
                acc = fma((double)xv.z, (double)wv4.z, acc);
                acc = fma((double)xv.w, (double)wv4.w, acc);
            }
            #pragma unroll
            for (int off = 32; off > 0; off >>= 1)
                acc += __shfl_xor(acc, off, 64);
            if (lane == e) mysc = acc;    // every lane keeps its expert's partial
        }
        part[wv][lane] = mysc;
        __syncthreads();
        if (wv == 0) {
            double s = (((part[0][lane] + part[1][lane]) + part[2][lane]) + part[3][lane])
                       + (double)bias[lane];
            double cv = s;
            for (int r = 0; r < TOPK_N; ++r) {
                double bv = cv;
                int    bi = lane;
                #pragma unroll
                for (int off = 32; off > 0; off >>= 1) {
                    const double ov = __shfl_xor(bv, off, 64);
                    const int    oi = __shfl_xor(bi, off, 64);
                    if (ov > bv || (ov == bv && oi < bi)) { bv = ov; bi = oi; }
                }
                if (lane == r)
                    out_idx[(size_t)tok * TOPK_N + r] = (float)bi;
                if (lane == bi) cv = -HUGE_VAL;
            }
        }
        __syncthreads();
    }
}

extern "C" void kernel_launch(void* const* d_in, const int* in_sizes, int n_in,
                              void* d_out, int out_size, void* d_ws, size_t ws_size,
                              hipStream_t stream) {
    const float* x  = (const float*)d_in[0];
    const float* w  = (const float*)d_in[1];
    const float* bs = (const float*)d_in[2];
    float* out = (float*)d_out;
    int*   flags = (int*)d_ws;

    const int ntok = in_sizes[0] / DIM;            // 8192
    const int grid = (ntok + BLK_TOK - 1) / BLK_TOK;   // 512

    hipMemsetAsync(flags, 0, sizeof(int), stream);
    hipLaunchKernelGGL(gate_kernel, dim3(grid), dim3(128), 0, stream,
                       x, w, bs, out, flags, ntok);
    hipLaunchKernelGGL(recheck_kernel, dim3(256), dim3(256), 0, stream,
                       x, w, bs, out, flags);
}

// Round 4
// 280.923 us; speedup vs baseline: 6.0434x; 6.0434x over previous
//
#include <hip/hip_runtime.h>
#include <math.h>

#define NTOK    8192
#define DIM     4096
#define NEXP    64
#define TOPK_N  8
#define TAU     2.0e-4f
#define MAXFLAG 4096

// ws layout (bytes): [0, 32K): flags (int count + token list); [32K, 32K+512K): w_hi bf16; then w_lo bf16
#define WS_WHI_OFF  32768
#define WS_WLO_OFF  (32768 + 524288)

typedef __attribute__((ext_vector_type(8))) short short8;   // 8 bf16 (4 VGPRs)
typedef __attribute__((ext_vector_type(4))) float f32x4;    // MFMA acc

// split fp32 -> bf16 hi (trunc) + bf16 lo (trunc of exact residual); pack 8 into a frag
__device__ __forceinline__ void cvt8(float4 a0, float4 a1, short8& hv, short8& lv) {
    float f[8] = {a0.x, a0.y, a0.z, a0.w, a1.x, a1.y, a1.z, a1.w};
    union { short8 v; unsigned u[4]; } H, L;
    #pragma unroll
    for (int i = 0; i < 4; ++i) {
        unsigned b0 = __float_as_uint(f[2*i]);
        unsigned b1 = __float_as_uint(f[2*i+1]);
        float r0 = f[2*i]   - __uint_as_float(b0 & 0xffff0000u);   // exact (Sterbenz)
        float r1 = f[2*i+1] - __uint_as_float(b1 & 0xffff0000u);
        H.u[i] = (b0 >> 16) | (b1 & 0xffff0000u);
        L.u[i] = (__float_as_uint(r0) >> 16) | (__float_as_uint(r1) & 0xffff0000u);
    }
    hv = H.v; lv = L.v;
}

// ---------------- Pass 0: convert w (fp32 [64][4096]) to bf16 hi/lo, row-major ----------------
__global__ __launch_bounds__(256, 4)
void cvt_w_kernel(const float* __restrict__ w, unsigned short* __restrict__ whi,
                  unsigned short* __restrict__ wlo) {
    const int g = blockIdx.x * 256 + threadIdx.x;     // 16384 threads, 16 elements each
    const float* p = w + (size_t)g * 16;
    union { short8 v; uint4 q; } H[2], L[2];
    #pragma unroll
    for (int h = 0; h < 2; ++h) {
        float4 a0 = *(const float4*)(p + h * 8);
        float4 a1 = *(const float4*)(p + h * 8 + 4);
        cvt8(a0, a1, H[h].v, L[h].v);
    }
    *(uint4*)(whi + (size_t)g * 16)     = H[0].q;
    *(uint4*)(whi + (size_t)g * 16 + 8) = H[1].q;
    *(uint4*)(wlo + (size_t)g * 16)     = L[0].q;
    *(uint4*)(wlo + (size_t)g * 16 + 8) = L[1].q;
}

// ---------------- Pass 1: MFMA bf16x3 GEMM + softmax + top-9 screen ----------------
// block = 512 thr = 8 waves = 2 m-groups x 4 k-splits. Block covers 32 tokens x 64 experts.
// Wave (mg,kq): m-frag of 16 tokens, 4 n-frags, K-range kq*1024..+1024, no LDS in K-loop.
__global__ __launch_bounds__(512, 2)
void gemm_kernel(const float* __restrict__ x, const unsigned short* __restrict__ whi,
                 const unsigned short* __restrict__ wlo, const float* __restrict__ bias,
                 float* __restrict__ out, int* __restrict__ flags, int ntok) {
    __shared__ float lds_acc[4 * 32 * 65];   // [kq][tok][e] padded stride 65 -> 33280 B
    __shared__ float lds_s[32 * 65];         // final scores                  ->  8320 B

    const int tid  = threadIdx.x;
    const int lane = tid & 63;
    const int wv   = tid >> 6;          // 0..7
    const int mg   = wv >> 2;           // 0..1  m-group
    const int kq   = wv & 3;            // 0..3  k-split
    const int nl   = lane & 15;
    const int q    = lane >> 4;
    const int tok0 = blockIdx.x * 32;

    f32x4 acc[4];
    #pragma unroll
    for (int nf = 0; nf < 4; ++nf) acc[nf] = (f32x4){0.f, 0.f, 0.f, 0.f};

    const int kbase = kq * (DIM / 4);
    const float* xrow = x + (size_t)(tok0 + mg * 16 + nl) * DIM;

    for (int ks = 0; ks < (DIM / 4) / 32; ++ks) {     // 32 k-steps of 32
        const int k0 = kbase + ks * 32 + q * 8;
        // A frag: 8 consecutive fp32 of this lane's token row
        float4 a0 = *(const float4*)(xrow + k0);
        float4 a1 = *(const float4*)(xrow + k0 + 4);
        short8 ahi, alo;
        cvt8(a0, a1, ahi, alo);
        // B frags straight from L2-resident pre-converted w
        short8 bhi[4], blo[4];
        #pragma unroll
        for (int nf = 0; nf < 4; ++nf) {
            const size_t off = (size_t)(nf * 16 + nl) * DIM + k0;
            bhi[nf] = *(const short8*)(whi + off);
            blo[nf] = *(const short8*)(wlo + off);
        }
        #pragma unroll
        for (int nf = 0; nf < 4; ++nf) {
            acc[nf] = __builtin_amdgcn_mfma_f32_16x16x32_bf16(ahi, blo[nf], acc[nf], 0, 0, 0);
            acc[nf] = __builtin_amdgcn_mfma_f32_16x16x32_bf16(alo, bhi[nf], acc[nf], 0, 0, 0);
            acc[nf] = __builtin_amdgcn_mfma_f32_16x16x32_bf16(ahi, bhi[nf], acc[nf], 0, 0, 0);
        }
    }

    // write k-partials to LDS: C/D layout col=lane&15, row=quad*4+reg
    #pragma unroll
    for (int nf = 0; nf < 4; ++nf)
        #pragma unroll
        for (int r = 0; r < 4; ++r) {
            const int tokl = mg * 16 + q * 4 + r;
            const int e    = nf * 16 + nl;
            lds_acc[kq * (32 * 65) + tokl * 65 + e] = acc[nf][r];
        }
    __syncthreads();

    // reduce 4 partials (fixed order -> deterministic), add bias
    #pragma unroll
    for (int i = 0; i < 4; ++i) {
        const int p  = tid + i * 512;
        const int tk = p >> 6, e = p & 63;
        float s = lds_acc[tk * 65 + e];
        #pragma unroll
        for (int k = 1; k < 4; ++k) s += lds_acc[k * (32 * 65) + tk * 65 + e];
        lds_s[tk * 65 + e] = s + bias[e];
    }
    __syncthreads();

    // softmax + top-9 screen: wave wv handles tokens wv*4..+4, lane = expert
    float* __restrict__ out_idx = out + (size_t)NTOK * NEXP;
    #pragma unroll
    for (int t = 0; t < 4; ++t) {
        const int tokl = wv * 4 + t;
        const int tok  = tok0 + tokl;
        const float s  = lds_s[tokl * 65 + lane];

        float m = s;
        #pragma unroll
        for (int off = 32; off > 0; off >>= 1)
            m = fmaxf(m, __shfl_xor(m, off, 64));
        const float ex = expf(s - m);
        float sum = ex;
        #pragma unroll
        for (int off = 32; off > 0; off >>= 1)
            sum += __shfl_xor(sum, off, 64);
        out[(size_t)tok * NEXP + lane] = ex / sum;

        float cv = s, prev = 0.f, ming = 1e30f;
        for (int r = 0; r < TOPK_N + 1; ++r) {
            float bv = cv;
            int   bi = lane;
            #pragma unroll
            for (int off = 32; off > 0; off >>= 1) {
                const float ov = __shfl_xor(bv, off, 64);
                const int   oi = __shfl_xor(bi, off, 64);
                if (ov > bv || (ov == bv && oi < bi)) { bv = ov; bi = oi; }
            }
            if (r > 0) ming = fminf(ming, prev - bv);
            prev = bv;
            if (r < TOPK_N && lane == r)
                out_idx[(size_t)tok * TOPK_N + r] = (float)bi;
            if (lane == bi) cv = -INFINITY;
        }
        if (lane == 0 && ming < TAU) {
            const int slot = atomicAdd(flags, 1);
            if (slot < MAXFLAG) flags[1 + slot] = tok;
        }
    }
}

// ---------------- Pass 2: fp64 recheck of flagged tokens, candidate-filtered ----------------
__global__ __launch_bounds__(256, 2)
void recheck_kernel(const float* __restrict__ x, const float* __restrict__ w,
                    const float* __restrict__ bias, float* __restrict__ out,
                    const int* __restrict__ flags) {
    __shared__ double dsc[NEXP];
    __shared__ int    cand[NEXP + 1];   // [0]=count
    int n = flags[0];
    if (n > MAXFLAG) n = MAXFLAG;
    const int lane = threadIdx.x & 63;
    const int wv   = threadIdx.x >> 6;
    float* __restrict__ out_idx = out + (size_t)NTOK * NEXP;

    for (int i = blockIdx.x; i < n; i += gridDim.x) {
        const int tok = flags[1 + i];
        if (wv == 0) {
            // candidate experts: prob within margin of the rank-8 prob
            const float pe  = out[(size_t)tok * NEXP + lane];
            const int   e8  = (int)out_idx[(size_t)tok * TOPK_N + 7];
            const float thr = out[(size_t)tok * NEXP + e8] * 0.999f;
            const unsigned long long msk = __ballot(pe >= thr);
            if (lane == 0) {
                int c = 0;
                unsigned long long mm = msk;
                while (mm) { cand[1 + c++] = __builtin_ctzll(mm); mm &= mm - 1; }
                cand[0] = c;
            }
            dsc[lane] = -1.0e300;
        }
        __syncthreads();
        const int nc = cand[0];
        for (int r = wv; r < nc; r += 4) {
            const int e = cand[1 + r];
            const float* wr = w + (size_t)e * DIM;
            const float* xr = x + (size_t)tok * DIM;
            double a = 0.0;
            #pragma unroll 4
            for (int kk = 0; kk < 16; ++kk) {
                const int k = kk * 256 + lane * 4;            // coalesced
                const float4 wv4 = *(const float4*)(wr + k);
                const float4 xv  = *(const float4*)(xr + k);
                a = fma((double)xv.x, (double)wv4.x, a);
                a = fma((double)xv.y, (double)wv4.y, a);
                a = fma((double)xv.z, (double)wv4.z, a);
                a = fma((double)xv.w, (double)wv4.w, a);
            }
            #pragma unroll
            for (int off = 32; off > 0; off >>= 1)
                a += __shfl_xor(a, off, 64);
            if (lane == 0) dsc[e] = a + (double)bias[e];
        }
        __syncthreads();
        if (wv == 0) {
            double cv = dsc[lane];
            for (int r = 0; r < TOPK_N; ++r) {
                double bv = cv;
                int    bi = lane;
                #pragma unroll
                for (int off = 32; off > 0; off >>= 1) {
                    const double ov = __shfl_xor(bv, off, 64);
                    const int    oi = __shfl_xor(bi, off, 64);
                    if (ov > bv || (ov == bv && oi < bi)) { bv = ov; bi = oi; }
                }
                if (lane == r)
                    out_idx[(size_t)tok * TOPK_N + r] = (float)bi;
                if (lane == bi) cv = -1.0e301;
            }
        }
        __syncthreads();
    }
}

extern "C" void kernel_launch(void* const* d_in, const int* in_sizes, int n_in,
                              void* d_out, int out_size, void* d_ws, size_t ws_size,
                              hipStream_t stream) {
    const float* x  = (const float*)d_in[0];
    const float* w  = (const float*)d_in[1];
    const float* bs = (const float*)d_in[2];
    float* out = (float*)d_out;

    int* flags = (int*)d_ws;
    unsigned short* whi = (unsigned short*)((char*)d_ws + WS_WHI_OFF);
    unsigned short* wlo = (unsigned short*)((char*)d_ws + WS_WLO_OFF);

    const int ntok = in_sizes[0] / DIM;          // 8192

    hipMemsetAsync(flags, 0, sizeof(int), stream);
    hipLaunchKernelGGL(cvt_w_kernel, dim3((NEXP * DIM) / 16 / 256), dim3(256), 0, stream,
                       w, whi, wlo);
    hipLaunchKernelGGL(gemm_kernel, dim3(ntok / 32), dim3(512), 0, stream,
                       x, whi, wlo, bs, out, flags, ntok);
    hipLaunchKernelGGL(recheck_kernel, dim3(256), dim3(256), 0, stream,
                       x, w, bs, out, flags);
}

// Round 5
// 254.988 us; speedup vs baseline: 6.6581x; 1.1017x over previous
//
#include <hip/hip_runtime.h>
#include <math.h>

#define NTOK    8192
#define DIM     4096
#define NEXP    64
#define TOPK_N  8
#define TAU     2.0e-4f
#define KSPLIT  8                  // waves per block = k-eighths
#define KSTEPS  ((DIM / KSPLIT) / 32)   // 16 k-steps of 32

#define WS_WHI_OFF  0
#define WS_WLO_OFF  524288

typedef __attribute__((ext_vector_type(8))) short short8;   // 8 bf16
typedef __attribute__((ext_vector_type(4))) float f32x4;

// fp32 -> bf16 hi (trunc) + bf16 lo (trunc of exact residual)
__device__ __forceinline__ void cvt8(float4 a0, float4 a1, short8& hv, short8& lv) {
    float f[8] = {a0.x, a0.y, a0.z, a0.w, a1.x, a1.y, a1.z, a1.w};
    union { short8 v; unsigned u[4]; } H, L;
    #pragma unroll
    for (int i = 0; i < 4; ++i) {
        unsigned b0 = __float_as_uint(f[2*i]);
        unsigned b1 = __float_as_uint(f[2*i+1]);
        float r0 = f[2*i]   - __uint_as_float(b0 & 0xffff0000u);
        float r1 = f[2*i+1] - __uint_as_float(b1 & 0xffff0000u);
        H.u[i] = (b0 >> 16) | (b1 & 0xffff0000u);
        L.u[i] = (__float_as_uint(r0) >> 16) | (__float_as_uint(r1) & 0xffff0000u);
    }
    hv = H.v; lv = L.v;
}

// ---------------- Pass 0: w fp32 -> bf16 hi/lo ----------------
__global__ __launch_bounds__(256, 4)
void cvt_w_kernel(const float* __restrict__ w, unsigned short* __restrict__ whi,
                  unsigned short* __restrict__ wlo) {
    const int g = blockIdx.x * 256 + threadIdx.x;
    const float* p = w + (size_t)g * 16;
    union { short8 v; uint4 q; } H[2], L[2];
    #pragma unroll
    for (int h = 0; h < 2; ++h) {
        float4 a0 = *(const float4*)(p + h * 8);
        float4 a1 = *(const float4*)(p + h * 8 + 4);
        cvt8(a0, a1, H[h].v, L[h].v);
    }
    *(uint4*)(whi + (size_t)g * 16)     = H[0].q;
    *(uint4*)(whi + (size_t)g * 16 + 8) = H[1].q;
    *(uint4*)(wlo + (size_t)g * 16)     = L[0].q;
    *(uint4*)(wlo + (size_t)g * 16 + 8) = L[1].q;
}

// ---------------- Pass 1: fused MFMA bf16x3 GEMM + softmax + top-8 + fp64 recheck ----------------
// block = 512 thr = 8 waves. Block covers 32 tokens x 64 experts.
// Wave wv = k-eighth; computes BOTH 16-token m-groups (B loaded once per k-step).
// No barriers in the K-loop; register double-buffered prefetch.
__global__ __launch_bounds__(512, 2)
void gemm_kernel(const float* __restrict__ x, const unsigned short* __restrict__ whi,
                 const unsigned short* __restrict__ wlo, const float* __restrict__ bias,
                 const float* __restrict__ wfp, float* __restrict__ out, int ntok) {
    __shared__ float  lds_part[KSPLIT][32][65];   // 66.6 KB
    __shared__ float  lds_s[32][65];              // 8.3 KB
    __shared__ double dsc[NEXP];
    __shared__ int    nflag;
    __shared__ int    ftok[32];
    __shared__ float  fninth[32];

    const int tid  = threadIdx.x;
    const int lane = tid & 63;
    const int wv   = tid >> 6;
    const int nl   = lane & 15;
    const int q    = lane >> 4;
    const int tok0 = blockIdx.x * 32;
    if (tid == 0) nflag = 0;

    const int kbase = wv * (DIM / KSPLIT);
    const float* xr[2] = { x + (size_t)(tok0 + nl) * DIM,
                           x + (size_t)(tok0 + 16 + nl) * DIM };
    size_t boff[4];
    #pragma unroll
    for (int nf = 0; nf < 4; ++nf) boff[nf] = (size_t)(nf * 16 + nl) * DIM;

    f32x4 acc[2][4];
    #pragma unroll
    for (int mg = 0; mg < 2; ++mg)
        #pragma unroll
        for (int nf = 0; nf < 4; ++nf) acc[mg][nf] = (f32x4){0.f, 0.f, 0.f, 0.f};

    float4 Ar[2][2][2];          // [buf][mg][half]
    short8 Bh[2][4], Bl[2][4];   // [buf][nf]

    // prologue loads (buf 0)
    {
        const int k0 = kbase + q * 8;
        #pragma unroll
        for (int mg = 0; mg < 2; ++mg) {
            Ar[0][mg][0] = *(const float4*)(xr[mg] + k0);
            Ar[0][mg][1] = *(const float4*)(xr[mg] + k0 + 4);
        }
        #pragma unroll
        for (int nf = 0; nf < 4; ++nf) {
            Bh[0][nf] = *(const short8*)(whi + boff[nf] + k0);
            Bl[0][nf] = *(const short8*)(wlo + boff[nf] + k0);
        }
    }

    #pragma unroll 2
    for (int ks = 0; ks < KSTEPS; ++ks) {
        const int buf = ks & 1, nxt = buf ^ 1;
        if (ks + 1 < KSTEPS) {   // prefetch next step
            const int k1 = kbase + (ks + 1) * 32 + q * 8;
            #pragma unroll
            for (int mg = 0; mg < 2; ++mg) {
                Ar[nxt][mg][0] = *(const float4*)(xr[mg] + k1);
                Ar[nxt][mg][1] = *(const float4*)(xr[mg] + k1 + 4);
            }
            #pragma unroll
            for (int nf = 0; nf < 4; ++nf) {
                Bh[nxt][nf] = *(const short8*)(whi + boff[nf] + k1);
                Bl[nxt][nf] = *(const short8*)(wlo + boff[nf] + k1);
            }
        }
        short8 ahi[2], alo[2];
        cvt8(Ar[buf][0][0], Ar[buf][0][1], ahi[0], alo[0]);
        cvt8(Ar[buf][1][0], Ar[buf][1][1], ahi[1], alo[1]);
        #pragma unroll
        for (int mg = 0; mg < 2; ++mg)
            #pragma unroll
            for (int nf = 0; nf < 4; ++nf) {
                acc[mg][nf] = __builtin_amdgcn_mfma_f32_16x16x32_bf16(ahi[mg], Bl[buf][nf], acc[mg][nf], 0, 0, 0);
                acc[mg][nf] = __builtin_amdgcn_mfma_f32_16x16x32_bf16(alo[mg], Bh[buf][nf], acc[mg][nf], 0, 0, 0);
                acc[mg][nf] = __builtin_amdgcn_mfma_f32_16x16x32_bf16(ahi[mg], Bh[buf][nf], acc[mg][nf], 0, 0, 0);
            }
    }

    // partials -> LDS (C/D layout: col=lane&15 -> expert, row=q*4+r -> token-in-group)
    #pragma unroll
    for (int mg = 0; mg < 2; ++mg)
        #pragma unroll
        for (int nf = 0; nf < 4; ++nf)
            #pragma unroll
            for (int r = 0; r < 4; ++r)
                lds_part[wv][mg * 16 + q * 4 + r][nf * 16 + nl] = acc[mg][nf][r];
    __syncthreads();

    // reduce 8 partials (fixed order), add bias
    #pragma unroll
    for (int i = 0; i < 4; ++i) {
        const int p  = tid + i * 512;
        const int tk = p >> 6, e = p & 63;
        float s = lds_part[0][tk][e];
        #pragma unroll
        for (int k = 1; k < KSPLIT; ++k) s += lds_part[k][tk][e];
        lds_s[tk][e] = s + bias[e];
    }
    __syncthreads();

    // softmax + top-9 screen: wave wv -> tokens wv*4..+4, lane = expert
    float* __restrict__ out_idx = out + (size_t)ntok * NEXP;
    #pragma unroll
    for (int t = 0; t < 4; ++t) {
        const int tokl = wv * 4 + t;
        const int tok  = tok0 + tokl;
        const float s  = lds_s[tokl][lane];

        float m = s;
        #pragma unroll
        for (int off = 32; off > 0; off >>= 1)
            m = fmaxf(m, __shfl_xor(m, off, 64));
        const float ex = expf(s - m);
        float sum = ex;
        #pragma unroll
        for (int off = 32; off > 0; off >>= 1)
            sum += __shfl_xor(sum, off, 64);
        out[(size_t)tok * NEXP + lane] = ex / sum;

        float cv = s, prev = 0.f, ming = 1e30f;
        for (int r = 0; r < TOPK_N + 1; ++r) {
            float bv = cv;
            int   bi = lane;
            #pragma unroll
            for (int off = 32; off > 0; off >>= 1) {
                const float ov = __shfl_xor(bv, off, 64);
                const int   oi = __shfl_xor(bi, off, 64);
                if (ov > bv || (ov == bv && oi < bi)) { bv = ov; bi = oi; }
            }
            if (r > 0) ming = fminf(ming, prev - bv);
            prev = bv;
            if (r < TOPK_N && lane == r)
                out_idx[(size_t)tok * TOPK_N + r] = (float)bi;
            if (lane == bi) cv = -INFINITY;
        }
        if (lane == 0 && ming < TAU) {
            const int sl = atomicAdd(&nflag, 1);
            ftok[sl] = tokl;
            fninth[sl] = prev;   // 9th-best fp32 score
        }
    }
    __syncthreads();

    // inline fp64 recheck of flagged tokens (block-local)
    const int nfl = nflag;
    for (int i = 0; i < nfl; ++i) {
        const int tokl = ftok[i];
        const int tok  = tok0 + tokl;
        const float thr = fninth[i] - TAU;
        // identical across waves (reads LDS): candidate mask
        const unsigned long long cmask = __ballot(lds_s[tokl][lane] >= thr);
        if (wv == 0) dsc[lane] = -1.0e300;
        __syncthreads();
        // wave wv handles candidate ranks wv, wv+8, ...
        {
            int rank = 0;
            unsigned long long mm = cmask;
            while (mm) {
                const int e = __builtin_ctzll(mm);
                mm &= mm - 1;
                if ((rank & 7) == wv) {
                    const float* wr = wfp + (size_t)e * DIM;
                    const float* xrr = x + (size_t)tok * DIM;
                    double a = 0.0;
                    #pragma unroll 4
                    for (int kk = 0; kk < 16; ++kk) {
                        const int k = kk * 256 + lane * 4;
                        const float4 wv4 = *(const float4*)(wr + k);
                        const float4 xv  = *(const float4*)(xrr + k);
                        a = fma((double)xv.x, (double)wv4.x, a);
                        a = fma((double)xv.y, (double)wv4.y, a);
                        a = fma((double)xv.z, (double)wv4.z, a);
                        a = fma((double)xv.w, (double)wv4.w, a);
                    }
                    #pragma unroll
                    for (int off = 32; off > 0; off >>= 1)
                        a += __shfl_xor(a, off, 64);
                    if (lane == 0) dsc[e] = a + (double)bias[e];
                }
                ++rank;
            }
        }
        __syncthreads();
        if (wv == 0) {
            double cv = dsc[lane];
            for (int r = 0; r < TOPK_N; ++r) {
                double bv = cv;
                int    bi = lane;
                #pragma unroll
                for (int off = 32; off > 0; off >>= 1) {
                    const double ov = __shfl_xor(bv, off, 64);
                    const int    oi = __shfl_xor(bi, off, 64);
                    if (ov > bv || (ov == bv && oi < bi)) { bv = ov; bi = oi; }
                }
                if (lane == r)
                    out_idx[(size_t)tok * TOPK_N + r] = (float)bi;
                if (lane == bi) cv = -1.0e301;
            }
        }
        __syncthreads();
    }
}

extern "C" void kernel_launch(void* const* d_in, const int* in_sizes, int n_in,
                              void* d_out, int out_size, void* d_ws, size_t ws_size,
                              hipStream_t stream) {
    const float* x  = (const float*)d_in[0];
    const float* w  = (const float*)d_in[1];
    const float* bs = (const float*)d_in[2];
    float* out = (float*)d_out;

    unsigned short* whi = (unsigned short*)((char*)d_ws + WS_WHI_OFF);
    unsigned short* wlo = (unsigned short*)((char*)d_ws + WS_WLO_OFF);

    const int ntok = in_sizes[0] / DIM;          // 8192

    hipLaunchKernelGGL(cvt_w_kernel, dim3((NEXP * DIM) / 16 / 256), dim3(256), 0, stream,
                       w, whi, wlo);
    hipLaunchKernelGGL(gemm_kernel, dim3(ntok / 32), dim3(512), 0, stream,
                       x, whi, wlo, bs, w, out, ntok);
}